// Round 1
// baseline (200.684 us; speedup 1.0000x reference)
//
#include <hip/hip_runtime.h>

#define HH 256
#define WW 256
#define KK 81
#define PLANE (HH * WW)

// Pack [B,3,H,W] planar fp32 -> [B,H,W] float4 (c0,c1,c2,0) so each bilinear
// corner gather is a single dwordx4 covering all 3 color groups.
__global__ __launch_bounds__(256) void pack_kernel(const float* __restrict__ in,
                                                   float4* __restrict__ img) {
    int idx = blockIdx.x * 256 + threadIdx.x;   // b*PLANE + pix
    int b = idx >> 16;
    int pix = idx & 0xFFFF;
    const float* base = in + (size_t)b * 3 * PLANE + pix;
    img[idx] = make_float4(base[0], base[PLANE], base[2 * PLANE], 0.f);
}

template <bool PACKED>
__global__ __launch_bounds__(256) void dcn_kernel(
    const float* __restrict__ input,
    const float4* __restrict__ img,
    const float* __restrict__ offset,
    const float* __restrict__ mask,
    const float* __restrict__ weight,
    const float* __restrict__ bias,
    float* __restrict__ out) {
    __shared__ float wk[KK];
    const int t = threadIdx.x;
    if (t < KK) wk[t] = weight[t];
    __syncthreads();

    const int wo = t;
    const int ho = blockIdx.x;
    const int b = blockIdx.y;

    const size_t row = (size_t)ho * WW + wo;
    const float* offp = offset + (size_t)b * 2 * KK * PLANE + row;
    const float* mskp = mask + (size_t)b * KK * PLANE + row;
    const float4* ib = img + (size_t)b * PLANE;
    const float* inb = input + (size_t)b * 3 * PLANE;

    float ax = 0.f, ay = 0.f, az = 0.f;

    int ky = 0, kx = 0;
#pragma unroll 9
    for (int k = 0; k < KK; ++k) {
        // streaming, fully coalesced reads (256 B / wave each)
        float dy = offp[(size_t)(2 * k) * PLANE];
        float dx = offp[(size_t)(2 * k + 1) * PLANE];
        float m = mskp[(size_t)k * PLANE] * wk[k];

        float py = (float)(ho - 4 + ky) + dy;
        float px = (float)(wo - 4 + kx) + dx;
        float y0f = floorf(py), x0f = floorf(px);
        float wy = py - y0f, wx = px - x0f;
        int y0 = (int)y0f, x0 = (int)x0f;
        int y1 = y0 + 1, x1 = x0 + 1;

        // validity folded into the separable bilinear weights (branch-free)
        float a0 = ((unsigned)y0 < (unsigned)HH) ? (1.f - wy) : 0.f;
        float a1 = ((unsigned)y1 < (unsigned)HH) ? wy : 0.f;
        float b0 = ((unsigned)x0 < (unsigned)WW) ? (1.f - wx) : 0.f;
        float b1 = ((unsigned)x1 < (unsigned)WW) ? wx : 0.f;

        int y0c = min(max(y0, 0), HH - 1) * WW;
        int y1c = min(max(y1, 0), HH - 1) * WW;
        int x0c = min(max(x0, 0), WW - 1);
        int x1c = min(max(x1, 0), WW - 1);

        float w00 = a0 * b0 * m;
        float w01 = a0 * b1 * m;
        float w10 = a1 * b0 * m;
        float w11 = a1 * b1 * m;

        if (PACKED) {
            float4 v00 = ib[y0c + x0c];
            float4 v01 = ib[y0c + x1c];
            float4 v10 = ib[y1c + x0c];
            float4 v11 = ib[y1c + x1c];
            ax = fmaf(w00, v00.x, ax);
            ay = fmaf(w00, v00.y, ay);
            az = fmaf(w00, v00.z, az);
            ax = fmaf(w01, v01.x, ax);
            ay = fmaf(w01, v01.y, ay);
            az = fmaf(w01, v01.z, az);
            ax = fmaf(w10, v10.x, ax);
            ay = fmaf(w10, v10.y, ay);
            az = fmaf(w10, v10.z, az);
            ax = fmaf(w11, v11.x, ax);
            ay = fmaf(w11, v11.y, ay);
            az = fmaf(w11, v11.z, az);
        } else {
            const float* p0 = inb;
            const float* p1 = inb + PLANE;
            const float* p2 = inb + 2 * PLANE;
            ax = fmaf(w00, p0[y0c + x0c], ax);
            ax = fmaf(w01, p0[y0c + x1c], ax);
            ax = fmaf(w10, p0[y1c + x0c], ax);
            ax = fmaf(w11, p0[y1c + x1c], ax);
            ay = fmaf(w00, p1[y0c + x0c], ay);
            ay = fmaf(w01, p1[y0c + x1c], ay);
            ay = fmaf(w10, p1[y1c + x0c], ay);
            ay = fmaf(w11, p1[y1c + x1c], ay);
            az = fmaf(w00, p2[y0c + x0c], az);
            az = fmaf(w01, p2[y0c + x1c], az);
            az = fmaf(w10, p2[y1c + x0c], az);
            az = fmaf(w11, p2[y1c + x1c], az);
        }

        kx++;
        if (kx == 9) {
            kx = 0;
            ky++;
        }
    }

    const float bv = bias[0];
    const size_t o = (size_t)b * 3 * PLANE + row;
    out[o] = ax + bv;
    out[o + PLANE] = ay + bv;
    out[o + 2 * PLANE] = az + bv;
}

extern "C" void kernel_launch(void* const* d_in, const int* in_sizes, int n_in,
                              void* d_out, int out_size, void* d_ws, size_t ws_size,
                              hipStream_t stream) {
    const float* input = (const float*)d_in[0];
    const float* offset = (const float*)d_in[1];
    const float* mask = (const float*)d_in[2];
    const float* weight = (const float*)d_in[3];
    const float* bias = (const float*)d_in[4];
    float* out = (float*)d_out;

    const int B = in_sizes[0] / (3 * PLANE);  // 2
    dim3 grid(HH, B);

    const size_t packed_bytes = (size_t)B * PLANE * sizeof(float4);
    if (ws_size >= packed_bytes) {
        float4* img = (float4*)d_ws;
        pack_kernel<<<B * PLANE / 256, 256, 0, stream>>>(input, img);
        dcn_kernel<true><<<grid, 256, 0, stream>>>(input, img, offset, mask, weight, bias, out);
    } else {
        dcn_kernel<false><<<grid, 256, 0, stream>>>(input, nullptr, offset, mask, weight, bias, out);
    }
}